// Round 5
// baseline (840.890 us; speedup 1.0000x reference)
//
#include <hip/hip_runtime.h>
#include <hip/hip_cooperative_groups.h>
#include <math.h>

namespace cg = cooperative_groups;

#define N 4096
#define H 64
#define MAXDEG 128
#define NEG_SLOPE 0.2f
#define LN_EPS 1e-5f

__device__ __forceinline__ float wave_reduce_sum(float v) {
    #pragma unroll
    for (int m = 32; m >= 1; m >>= 1) v += __shfl_xor(v, m, 64);
    return v;
}
__device__ __forceinline__ float wave_reduce_max(float v) {
    #pragma unroll
    for (int m = 32; m >= 1; m >>= 1) v = fmaxf(v, __shfl_xor(v, m, 64));
    return v;
}

// row-vector (held across wave: lane=col) times 64x64 W, W row-major.
__device__ __forceinline__ float transform_row(float hv, const float* __restrict__ W,
                                               int lane) {
    float tr = 0.f;
    #pragma unroll
    for (int k = 0; k < 64; ++k)
        tr += __shfl(hv, k, 64) * W[k * 64 + lane];
    return tr;
}

// softmax over neighbors of row i + weighted aggregation of hwin rows + bias.
__device__ __forceinline__ float aggregate_row(int i, int lane,
        const float* __restrict__ hwin, const float* __restrict__ ssin, float sd,
        const int* __restrict__ nbr, int deg, const float* __restrict__ b) {
    int j0 = 0, j1 = 0;
    float e0 = -1e30f, e1 = -1e30f;
    if (lane < deg) {
        j0 = nbr[i * MAXDEG + lane];
        float v = ssin[j0] + sd;
        e0 = v > 0.f ? v : NEG_SLOPE * v;
    }
    if (lane + 64 < deg) {
        j1 = nbr[i * MAXDEG + lane + 64];
        float v = ssin[j1] + sd;
        e1 = v > 0.f ? v : NEG_SLOPE * v;
    }
    float m = wave_reduce_max(fmaxf(e0, e1));
    float p0 = (lane < deg) ? expf(e0 - m) : 0.f;
    float p1 = (lane + 64 < deg) ? expf(e1 - m) : 0.f;
    float Z = wave_reduce_sum(p0 + p1);
    float acc = 0.f;
    int d0 = min(deg, 64);
    #pragma unroll 4
    for (int n = 0; n < d0; ++n) {
        int   jj = __shfl(j0, n, 64);
        float p  = __shfl(p0, n, 64);
        acc += p * hwin[jj * 64 + lane];
    }
    for (int n = 64; n < deg; ++n) {
        int   jj = __shfl(j1, n - 64, 64);
        float p  = __shfl(p1, n - 64, 64);
        acc += p * hwin[jj * 64 + lane];
    }
    return acc / Z + b[lane];
}

// ---------------- cooperative single-kernel path ----------------
// 256 blocks x 1024 threads = 1 block/CU (co-residency guaranteed),
// 4096 waves -> one wave per row. VGPR capped at 128 via launch_bounds.
__global__ void __launch_bounds__(1024, 4) gat_fused(
        const float4* __restrict__ adj4, const int* __restrict__ timestep,
        const float* __restrict__ arr, const float* __restrict__ dep,
        const float* __restrict__ hard,
        const float* __restrict__ w1, const float* __restrict__ b1,
        const float* __restrict__ w2, const float* __restrict__ b2,
        const float* __restrict__ gat_w, const float* __restrict__ gat_asrc,
        const float* __restrict__ gat_adst, const float* __restrict__ gat_b,
        const float* __restrict__ vw, const float* __restrict__ vb,
        int* __restrict__ cnt, int* __restrict__ nbr,
        float* __restrict__ x, float* __restrict__ hwA, float* __restrict__ hwB,
        float* __restrict__ ssA, float* __restrict__ sdA,
        float* __restrict__ ssB, float* __restrict__ sdB,
        float* __restrict__ partial, float* __restrict__ out) {
    cg::grid_group grid = cg::this_grid();
    int tid  = blockIdx.x * 1024 + threadIdx.x;  // 0..262143
    int wave = threadIdx.x >> 6;                 // 0..15
    int lane = threadIdx.x & 63;
    int row  = blockIdx.x * 16 + wave;           // 0..4095

    // ---- phase 0: zero counters ----
    if (tid < N) cnt[tid] = 0;
    __threadfence();
    grid.sync();

    // ---- phase 1: neighbor build (1M items, 4/thread; item = 4 cols x 4 rows) ----
    for (int r = 0; r < 4; ++r) {
        int item  = tid + r * 262144;
        int cgi   = item & 1023;
        int band  = item >> 10;
        int i0    = cgi * 4;
        int jbase = band * 4;
        float4 a[4];
        #pragma unroll
        for (int jj = 0; jj < 4; ++jj)
            a[jj] = adj4[(size_t)(jbase + jj) * 1024 + cgi];
        #pragma unroll
        for (int jj = 0; jj < 4; ++jj) {
            int j = jbase + jj;
            if (a[jj].x != 0.f || j == i0)     { int p = atomicAdd(&cnt[i0],   1); if (p < MAXDEG) nbr[ i0      * MAXDEG + p] = j; }
            if (a[jj].y != 0.f || j == i0 + 1) { int p = atomicAdd(&cnt[i0+1], 1); if (p < MAXDEG) nbr[(i0 + 1) * MAXDEG + p] = j; }
            if (a[jj].z != 0.f || j == i0 + 2) { int p = atomicAdd(&cnt[i0+2], 1); if (p < MAXDEG) nbr[(i0 + 2) * MAXDEG + p] = j; }
            if (a[jj].w != 0.f || j == i0 + 3) { int p = atomicAdd(&cnt[i0+3], 1); if (p < MAXDEG) nbr[(i0 + 3) * MAXDEG + p] = j; }
        }
    }
    __threadfence();
    grid.sync();

    // ---- phase 2: embedding MLP + layer-0 transform + scores ----
    {
        float ts = (float)(*timestep);
        float pr = (ts - arr[row]) / (dep[row] - arr[row]);
        float hd = hard[row];
        float t  = pr * w1[lane] + hd * w1[64 + lane] + b1[lane];
        float xv = b2[lane];
        #pragma unroll
        for (int k = 0; k < 64; ++k)
            xv += __shfl(t, k, 64) * w2[k * 64 + lane];
        x[row * 64 + lane] = xv;
        float tr = transform_row(xv, gat_w, lane);
        hwA[row * 64 + lane] = tr;
        float s1 = wave_reduce_sum(tr * gat_asrc[lane]);
        float s2 = wave_reduce_sum(tr * gat_adst[lane]);
        if (lane == 0) { ssA[row] = s1; sdA[row] = s2; }
    }
    __threadfence();
    grid.sync();

    int deg = min(cnt[row], MAXDEG);

    // ---- phase 3: layer-0 aggregate + relu + layer-1 transform ----
    {
        float hv = fmaxf(aggregate_row(row, lane, hwA, ssA, sdA[row], nbr, deg, gat_b), 0.f);
        float tr = transform_row(hv, gat_w + 64 * 64, lane);
        hwB[row * 64 + lane] = tr;
        float s1 = wave_reduce_sum(tr * gat_asrc[64 + lane]);
        float s2 = wave_reduce_sum(tr * gat_adst[64 + lane]);
        if (lane == 0) { ssB[row] = s1; sdB[row] = s2; }
    }
    __threadfence();
    grid.sync();

    // ---- phase 4: layer-1 aggregate + relu + layer-2 transform ----
    {
        float hv = fmaxf(aggregate_row(row, lane, hwB, ssB, sdB[row], nbr, deg, gat_b + 64), 0.f);
        float tr = transform_row(hv, gat_w + 2 * 64 * 64, lane);
        hwA[row * 64 + lane] = tr;
        float s1 = wave_reduce_sum(tr * gat_asrc[128 + lane]);
        float s2 = wave_reduce_sum(tr * gat_adst[128 + lane]);
        if (lane == 0) { ssA[row] = s1; sdA[row] = s2; }
    }
    __threadfence();
    grid.sync();

    // ---- phase 5: layer-2 aggregate + residual + layernorm + val_w dot ----
    {
        float hv = aggregate_row(row, lane, hwA, ssA, sdA[row], nbr, deg, gat_b + 128);
        float v  = x[row * 64 + lane] + hv;
        float mu = wave_reduce_sum(v) * (1.f / 64.f);
        float d  = v - mu;
        float var = wave_reduce_sum(d * d) * (1.f / 64.f);
        float ln  = d * rsqrtf(var + LN_EPS);
        float part = wave_reduce_sum(ln * vw[lane]);
        if (lane == 0) partial[row] = part;
    }
    __threadfence();
    grid.sync();

    // ---- phase 6: final reduction (block 0) ----
    if (blockIdx.x == 0) {
        __shared__ float s[16];
        float v = 0.f;
        for (int k = threadIdx.x; k < N; k += 1024) v += partial[k];
        v = wave_reduce_sum(v);
        if (lane == 0) s[wave] = v;
        __syncthreads();
        if (threadIdx.x == 0) {
            float t = 0.f;
            #pragma unroll
            for (int w = 0; w < 16; ++w) t += s[w];
            out[0] = fmaxf(t * (1.f / (float)N) + vb[0], 0.f);
        }
    }
}

// ---------------- fallback multi-kernel path (proven in R3) ----------------
__global__ void build_nbr(const float4* __restrict__ adj4,
                          int* __restrict__ cnt, int* __restrict__ nbr) {
    int t = blockIdx.x * blockDim.x + threadIdx.x;
    int cgi = t & 1023;
    int band = t >> 10;
    int i0 = cgi * 4;
    int jbase = band * 4;
    float4 a[4];
    #pragma unroll
    for (int jj = 0; jj < 4; ++jj)
        a[jj] = adj4[(size_t)(jbase + jj) * 1024 + cgi];
    #pragma unroll
    for (int jj = 0; jj < 4; ++jj) {
        int j = jbase + jj;
        if (a[jj].x != 0.f || j == i0)     { int p = atomicAdd(&cnt[i0],   1); if (p < MAXDEG) nbr[ i0      * MAXDEG + p] = j; }
        if (a[jj].y != 0.f || j == i0 + 1) { int p = atomicAdd(&cnt[i0+1], 1); if (p < MAXDEG) nbr[(i0 + 1) * MAXDEG + p] = j; }
        if (a[jj].z != 0.f || j == i0 + 2) { int p = atomicAdd(&cnt[i0+2], 1); if (p < MAXDEG) nbr[(i0 + 2) * MAXDEG + p] = j; }
        if (a[jj].w != 0.f || j == i0 + 3) { int p = atomicAdd(&cnt[i0+3], 1); if (p < MAXDEG) nbr[(i0 + 3) * MAXDEG + p] = j; }
    }
}

__global__ void emb_tr0(const int* __restrict__ timestep,
                        const float* __restrict__ arr, const float* __restrict__ dep,
                        const float* __restrict__ hard,
                        const float* __restrict__ w1, const float* __restrict__ b1,
                        const float* __restrict__ w2, const float* __restrict__ b2,
                        const float* __restrict__ W0, const float* __restrict__ asrc,
                        const float* __restrict__ adst,
                        float* __restrict__ x, float* __restrict__ hw,
                        float* __restrict__ ssrc, float* __restrict__ sdst) {
    int wave = threadIdx.x >> 6;
    int lane = threadIdx.x & 63;
    int i = blockIdx.x * 4 + wave;
    float ts = (float)(*timestep);
    float pr = (ts - arr[i]) / (dep[i] - arr[i]);
    float hd = hard[i];
    float t = pr * w1[lane] + hd * w1[64 + lane] + b1[lane];
    float xv = b2[lane];
    #pragma unroll
    for (int k = 0; k < 64; ++k)
        xv += __shfl(t, k, 64) * w2[k * 64 + lane];
    x[i * 64 + lane] = xv;
    float tr = transform_row(xv, W0, lane);
    hw[i * 64 + lane] = tr;
    float s1 = wave_reduce_sum(tr * asrc[lane]);
    float s2 = wave_reduce_sum(tr * adst[lane]);
    if (lane == 0) { ssrc[i] = s1; sdst[i] = s2; }
}

__global__ void agg_tr(const float* __restrict__ hwin, const float* __restrict__ ssin,
                       const float* __restrict__ sdin, const int* __restrict__ nbr,
                       const int* __restrict__ cnt, const float* __restrict__ b,
                       const float* __restrict__ W, const float* __restrict__ asrc,
                       const float* __restrict__ adst,
                       float* __restrict__ hwout, float* __restrict__ ssout,
                       float* __restrict__ sdout) {
    int wave = threadIdx.x >> 6;
    int lane = threadIdx.x & 63;
    int i = blockIdx.x * 4 + wave;
    int deg = min(cnt[i], MAXDEG);
    float hv = fmaxf(aggregate_row(i, lane, hwin, ssin, sdin[i], nbr, deg, b), 0.f);
    float tr = transform_row(hv, W, lane);
    hwout[i * 64 + lane] = tr;
    float s1 = wave_reduce_sum(tr * asrc[lane]);
    float s2 = wave_reduce_sum(tr * adst[lane]);
    if (lane == 0) { ssout[i] = s1; sdout[i] = s2; }
}

__global__ void agg_final(const float* __restrict__ hwin, const float* __restrict__ ssin,
                          const float* __restrict__ sdin, const int* __restrict__ nbr,
                          const int* __restrict__ cnt, const float* __restrict__ b,
                          const float* __restrict__ x, const float* __restrict__ vw,
                          float* __restrict__ partial) {
    int wave = threadIdx.x >> 6;
    int lane = threadIdx.x & 63;
    int i = blockIdx.x * 4 + wave;
    int deg = min(cnt[i], MAXDEG);
    float hv = aggregate_row(i, lane, hwin, ssin, sdin[i], nbr, deg, b);
    float v = x[i * 64 + lane] + hv;
    float mu = wave_reduce_sum(v) * (1.f / 64.f);
    float d = v - mu;
    float var = wave_reduce_sum(d * d) * (1.f / 64.f);
    float ln = d * rsqrtf(var + LN_EPS);
    float part = wave_reduce_sum(ln * vw[lane]);
    if (lane == 0) partial[i] = part;
}

__global__ void reduce_out(const float* __restrict__ partial,
                           const float* __restrict__ val_b, float* __restrict__ out) {
    __shared__ float s[4];
    int wave = threadIdx.x >> 6;
    int lane = threadIdx.x & 63;
    float v = 0.f;
    for (int k = threadIdx.x; k < N; k += 256) v += partial[k];
    v = wave_reduce_sum(v);
    if (lane == 0) s[wave] = v;
    __syncthreads();
    if (threadIdx.x == 0) {
        float t = s[0] + s[1] + s[2] + s[3];
        out[0] = fmaxf(t * (1.f / (float)N) + val_b[0], 0.f);
    }
}

extern "C" void kernel_launch(void* const* d_in, const int* in_sizes, int n_in,
                              void* d_out, int out_size, void* d_ws, size_t ws_size,
                              hipStream_t stream) {
    const float4* adj4      = (const float4*)d_in[0];
    const float*  adj       = (const float*)d_in[0];
    const int*   timestep   = (const int*)  d_in[1];
    const float* arrivals   = (const float*)d_in[2];
    const float* departures = (const float*)d_in[3];
    const float* hard       = (const float*)d_in[4];
    // d_in[5] active_agents: unused by reference
    const float* emb_w1     = (const float*)d_in[6];
    const float* emb_b1     = (const float*)d_in[7];
    const float* emb_w2     = (const float*)d_in[8];
    const float* emb_b2     = (const float*)d_in[9];
    const float* gat_w      = (const float*)d_in[10];
    const float* gat_asrc   = (const float*)d_in[11];
    const float* gat_adst   = (const float*)d_in[12];
    const float* gat_b      = (const float*)d_in[13];
    const float* val_w      = (const float*)d_in[14];
    const float* val_b      = (const float*)d_in[15];

    char* ws = (char*)d_ws;
    int*   cnt     = (int*)  (ws);                    // 16 KB
    float* partial = (float*)(ws + 16384);            // 16 KB
    int*   nbr     = (int*)  (ws + 65536);            // 2 MB
    float* x       = (float*)(ws + (4u << 20));       // 1 MB
    float* hwA     = (float*)(ws + (5u << 20));       // 1 MB
    float* hwB     = (float*)(ws + (6u << 20));       // 1 MB
    float* ssA     = (float*)(ws + (7u << 20));
    float* sdA     = (float*)(ws + (7u << 20) + 65536);
    float* ssB     = (float*)(ws + (7u << 20) + 131072);
    float* sdB     = (float*)(ws + (7u << 20) + 196608);
    float* outp    = (float*)d_out;

    void* args[] = {
        (void*)&adj4, (void*)&timestep, (void*)&arrivals, (void*)&departures,
        (void*)&hard, (void*)&emb_w1, (void*)&emb_b1, (void*)&emb_w2, (void*)&emb_b2,
        (void*)&gat_w, (void*)&gat_asrc, (void*)&gat_adst, (void*)&gat_b,
        (void*)&val_w, (void*)&val_b,
        (void*)&cnt, (void*)&nbr, (void*)&x, (void*)&hwA, (void*)&hwB,
        (void*)&ssA, (void*)&sdA, (void*)&ssB, (void*)&sdB,
        (void*)&partial, (void*)&outp
    };
    hipError_t err = hipLaunchCooperativeKernel((const void*)gat_fused, dim3(256),
                                                dim3(1024), args, 0, stream);
    if (err != hipSuccess) {
        // Fallback: proven multi-kernel sequence (identical math).
        hipMemsetAsync(cnt, 0, 16384, stream);
        build_nbr<<<4096, 256, 0, stream>>>(adj4, cnt, nbr);
        emb_tr0<<<N / 4, 256, 0, stream>>>(timestep, arrivals, departures, hard,
                                           emb_w1, emb_b1, emb_w2, emb_b2,
                                           gat_w, gat_asrc, gat_adst,
                                           x, hwA, ssA, sdA);
        agg_tr<<<N / 4, 256, 0, stream>>>(hwA, ssA, sdA, nbr, cnt, gat_b,
                                          gat_w + 64 * 64, gat_asrc + 64, gat_adst + 64,
                                          hwB, ssB, sdB);
        agg_tr<<<N / 4, 256, 0, stream>>>(hwB, ssB, sdB, nbr, cnt, gat_b + 64,
                                          gat_w + 2 * 64 * 64, gat_asrc + 128, gat_adst + 128,
                                          hwA, ssA, sdA);
        agg_final<<<N / 4, 256, 0, stream>>>(hwA, ssA, sdA, nbr, cnt, gat_b + 128,
                                             x, val_w, partial);
        reduce_out<<<1, 256, 0, stream>>>(partial, val_b, (float*)d_out);
    }
    (void)adj; (void)in_sizes; (void)n_in; (void)out_size; (void)ws_size;
}

// Round 6
// 240.269 us; speedup vs baseline: 3.4998x; 3.4998x over previous
//
#include <hip/hip_runtime.h>
#include <math.h>

#define N 4096
#define NB 32          // bands per row
#define BANDSZ 128     // rows per band
#define KB 16          // slots per (row, band) cell
#define MAXDEG 128
#define NEG_SLOPE 0.2f
#define LN_EPS 1e-5f

__device__ __forceinline__ float wave_reduce_sum(float v) {
    #pragma unroll
    for (int m = 32; m >= 1; m >>= 1) v += __shfl_xor(v, m, 64);
    return v;
}
__device__ __forceinline__ float wave_reduce_max(float v) {
    #pragma unroll
    for (int m = 32; m >= 1; m >>= 1) v = fmaxf(v, __shfl_xor(v, m, 64));
    return v;
}

// row-vector (lane=col) times 64x64 row-major W via shfl broadcast.
__device__ __forceinline__ float transform_row(float hv, const float* __restrict__ W,
                                               int lane) {
    float tr = 0.f;
    #pragma unroll
    for (int k = 0; k < 64; ++k)
        tr += __shfl(hv, k, 64) * W[k * 64 + lane];
    return tr;
}

// softmax over neighbors (j0: first 64, j1: next 64, deg total) + weighted
// aggregation of hwin rows + bias. Indices/probs broadcast via shfl.
__device__ __forceinline__ float agg_core(int j0, int j1, int deg, float sd,
        const float* __restrict__ ssin, const float* __restrict__ hwin,
        const float* __restrict__ b, int lane) {
    float e0 = -1e30f, e1 = -1e30f;
    if (lane < deg)      { float v = ssin[j0] + sd; e0 = v > 0.f ? v : NEG_SLOPE * v; }
    if (lane + 64 < deg) { float v = ssin[j1] + sd; e1 = v > 0.f ? v : NEG_SLOPE * v; }
    float m = wave_reduce_max(fmaxf(e0, e1));
    float p0 = (lane < deg)      ? expf(e0 - m) : 0.f;
    float p1 = (lane + 64 < deg) ? expf(e1 - m) : 0.f;
    float Z = wave_reduce_sum(p0 + p1);
    float acc = 0.f;
    int d0 = min(deg, 64);
    #pragma unroll 4
    for (int n = 0; n < d0; ++n) {
        int   jj = __shfl(j0, n, 64);
        float p  = __shfl(p0, n, 64);
        acc += p * hwin[jj * 64 + lane];
    }
    for (int n = 64; n < deg; ++n) {
        int   jj = __shfl(j1, n - 64, 64);
        float p  = __shfl(p1, n - 64, 64);
        acc += p * hwin[jj * 64 + lane];
    }
    return acc / Z + b[lane];
}

// ---- dispatch 1: banded neighbor build (atomic-free) + emb MLP + layer-0
// transform. Blocks [0,512): build — wave owns 64 consecutive cols x 1 band,
// every load is a coalesced 256B line, per-thread private slot lists.
// Blocks [512,1536): emb+tr0 (independent work, merged to save a dispatch).
__global__ void __launch_bounds__(256) prep_kernel(
        const float* __restrict__ adj, const int* __restrict__ timestep,
        const float* __restrict__ arr, const float* __restrict__ dep,
        const float* __restrict__ hard,
        const float* __restrict__ w1, const float* __restrict__ b1,
        const float* __restrict__ w2, const float* __restrict__ b2,
        const float* __restrict__ W0, const float* __restrict__ asrc,
        const float* __restrict__ adst,
        int* __restrict__ nbr2, int* __restrict__ cnt2,
        float* __restrict__ x, float* __restrict__ hwA,
        float* __restrict__ ssA, float* __restrict__ sdA,
        float* __restrict__ accum, int* __restrict__ done) {
    int wave = threadIdx.x >> 6;
    int lane = threadIdx.x & 63;
    if (blockIdx.x < 512) {
        int gw   = blockIdx.x * 4 + wave;    // 0..2047
        int band = gw & (NB - 1);
        int cg   = gw >> 5;                  // 0..63 col-group
        int i    = cg * 64 + lane;           // this thread's column
        int jbase = band * BANDSZ;
        int base  = (i * NB + band) * KB;
        int lc = 0;
        #pragma unroll 4
        for (int t = 0; t < BANDSZ; ++t) {
            int j = jbase + t;
            float a = adj[(size_t)j * N + i];
            if (a != 0.f || j == i) {        // edge j->i, plus self-loop
                if (lc < KB) nbr2[base + lc] = j;
                ++lc;
            }
        }
        cnt2[i * NB + band] = lc < KB ? lc : KB;
        if (blockIdx.x == 0 && threadIdx.x == 0) { *accum = 0.f; *done = 0; }
    } else {
        int row = (blockIdx.x - 512) * 4 + wave;
        float ts = (float)(*timestep);
        float pr = (ts - arr[row]) / (dep[row] - arr[row]);
        float hd = hard[row];
        float t  = pr * w1[lane] + hd * w1[64 + lane] + b1[lane];
        float xv = b2[lane];
        #pragma unroll
        for (int k = 0; k < 64; ++k)
            xv += __shfl(t, k, 64) * w2[k * 64 + lane];
        x[row * 64 + lane] = xv;
        float tr = transform_row(xv, W0, lane);
        hwA[row * 64 + lane] = tr;
        float s1 = wave_reduce_sum(tr * asrc[lane]);
        float s2 = wave_reduce_sum(tr * adst[lane]);
        if (lane == 0) { ssA[row] = s1; sdA[row] = s2; }
    }
}

// ---- dispatch 2: compact banded lists (once; reused by later layers) +
// layer-0 aggregate + relu + layer-1 transform + scores.
__global__ void __launch_bounds__(256) compact_agg_tr(
        const int* __restrict__ nbr2, const int* __restrict__ cnt2,
        const float* __restrict__ hwin, const float* __restrict__ ssin,
        const float* __restrict__ sdin, const float* __restrict__ b,
        const float* __restrict__ W, const float* __restrict__ asrc,
        const float* __restrict__ adst,
        int* __restrict__ nbr_c, int* __restrict__ deg_arr,
        float* __restrict__ hwout, float* __restrict__ ssout,
        float* __restrict__ sdout) {
    __shared__ int lds[4][MAXDEG];
    int wave = threadIdx.x >> 6;
    int lane = threadIdx.x & 63;
    int i = blockIdx.x * 4 + wave;
    // per-band counts -> wave prefix scan -> compact into LDS
    int c = (lane < NB) ? min(cnt2[i * NB + lane], KB) : 0;
    int inc = c;
    #pragma unroll
    for (int s = 1; s < 64; s <<= 1) {
        int t = __shfl_up(inc, s, 64);
        if (lane >= s) inc += t;
    }
    int off = inc - c;
    int deg = min(__shfl(inc, 63, 64), MAXDEG);
    if (lane < NB) {
        int base = (i * NB + lane) * KB;
        for (int k = 0; k < c; ++k) {
            int o = off + k;
            if (o < MAXDEG) lds[wave][o] = nbr2[base + k];
        }
    }
    __syncthreads();
    int j0 = (lane < deg)      ? lds[wave][lane]      : 0;
    int j1 = (lane + 64 < deg) ? lds[wave][lane + 64] : 0;
    if (lane < deg)      nbr_c[i * MAXDEG + lane]      = j0;
    if (lane + 64 < deg) nbr_c[i * MAXDEG + lane + 64] = j1;
    if (lane == 0) deg_arr[i] = deg;
    // layer-0 aggregate + relu + layer-1 transform
    float hv = fmaxf(agg_core(j0, j1, deg, sdin[i], ssin, hwin, b, lane), 0.f);
    float tr = transform_row(hv, W, lane);
    hwout[i * 64 + lane] = tr;
    float s1 = wave_reduce_sum(tr * asrc[lane]);
    float s2 = wave_reduce_sum(tr * adst[lane]);
    if (lane == 0) { ssout[i] = s1; sdout[i] = s2; }
}

// ---- dispatch 3: layer-1 aggregate + relu + layer-2 transform + scores.
__global__ void __launch_bounds__(256) agg_tr(
        const float* __restrict__ hwin, const float* __restrict__ ssin,
        const float* __restrict__ sdin, const int* __restrict__ nbr_c,
        const int* __restrict__ deg_arr, const float* __restrict__ b,
        const float* __restrict__ W, const float* __restrict__ asrc,
        const float* __restrict__ adst,
        float* __restrict__ hwout, float* __restrict__ ssout,
        float* __restrict__ sdout) {
    int wave = threadIdx.x >> 6;
    int lane = threadIdx.x & 63;
    int i = blockIdx.x * 4 + wave;
    int deg = deg_arr[i];
    int j0 = (lane < deg)      ? nbr_c[i * MAXDEG + lane]      : 0;
    int j1 = (lane + 64 < deg) ? nbr_c[i * MAXDEG + lane + 64] : 0;
    float hv = fmaxf(agg_core(j0, j1, deg, sdin[i], ssin, hwin, b, lane), 0.f);
    float tr = transform_row(hv, W, lane);
    hwout[i * 64 + lane] = tr;
    float s1 = wave_reduce_sum(tr * asrc[lane]);
    float s2 = wave_reduce_sum(tr * adst[lane]);
    if (lane == 0) { ssout[i] = s1; sdout[i] = s2; }
}

// ---- dispatch 4: layer-2 aggregate + residual + layernorm + val_w dot +
// block atomicAdd + last-block finish (done/accum pre-zeroed by dispatch 1).
__global__ void __launch_bounds__(256) agg_final_finish(
        const float* __restrict__ hwin, const float* __restrict__ ssin,
        const float* __restrict__ sdin, const int* __restrict__ nbr_c,
        const int* __restrict__ deg_arr, const float* __restrict__ b,
        const float* __restrict__ x, const float* __restrict__ vw,
        const float* __restrict__ vb,
        float* __restrict__ accum, int* __restrict__ done,
        float* __restrict__ out) {
    __shared__ float sp[4];
    int wave = threadIdx.x >> 6;
    int lane = threadIdx.x & 63;
    int i = blockIdx.x * 4 + wave;
    int deg = deg_arr[i];
    int j0 = (lane < deg)      ? nbr_c[i * MAXDEG + lane]      : 0;
    int j1 = (lane + 64 < deg) ? nbr_c[i * MAXDEG + lane + 64] : 0;
    float hv = agg_core(j0, j1, deg, sdin[i], ssin, hwin, b, lane);
    float v  = x[i * 64 + lane] + hv;
    float mu = wave_reduce_sum(v) * (1.f / 64.f);
    float d  = v - mu;
    float var = wave_reduce_sum(d * d) * (1.f / 64.f);
    float ln  = d * rsqrtf(var + LN_EPS);
    float part = wave_reduce_sum(ln * vw[lane]);
    if (lane == 0) sp[wave] = part;
    __syncthreads();
    if (threadIdx.x == 0) {
        float bp = sp[0] + sp[1] + sp[2] + sp[3];
        atomicAdd(accum, bp);                 // one atomic per block (1024)
        __threadfence();
        int old = atomicAdd(done, 1);
        if (old == (N / 4) - 1) {             // last block: finish
            float t = __hip_atomic_load(accum, __ATOMIC_RELAXED,
                                        __HIP_MEMORY_SCOPE_AGENT);
            out[0] = fmaxf(t * (1.f / (float)N) + vb[0], 0.f);
        }
    }
}

extern "C" void kernel_launch(void* const* d_in, const int* in_sizes, int n_in,
                              void* d_out, int out_size, void* d_ws, size_t ws_size,
                              hipStream_t stream) {
    const float* adj        = (const float*)d_in[0];
    const int*   timestep   = (const int*)  d_in[1];
    const float* arrivals   = (const float*)d_in[2];
    const float* departures = (const float*)d_in[3];
    const float* hard       = (const float*)d_in[4];
    // d_in[5] active_agents: unused by reference
    const float* emb_w1     = (const float*)d_in[6];
    const float* emb_b1     = (const float*)d_in[7];
    const float* emb_w2     = (const float*)d_in[8];
    const float* emb_b2     = (const float*)d_in[9];
    const float* gat_w      = (const float*)d_in[10];
    const float* gat_asrc   = (const float*)d_in[11];
    const float* gat_adst   = (const float*)d_in[12];
    const float* gat_b      = (const float*)d_in[13];
    const float* val_w      = (const float*)d_in[14];
    const float* val_b      = (const float*)d_in[15];

    const size_t MB = 1u << 20;
    char* ws = (char*)d_ws;
    int*   nbr2    = (int*)  (ws);                 // 8 MB  (4096*32*16 ints)
    int*   cnt2    = (int*)  (ws + 8 * MB);        // 512 KB
    int*   nbr_c   = (int*)  (ws + 9 * MB);        // 2 MB
    int*   deg_arr = (int*)  (ws + 11 * MB);       // 16 KB
    float* x       = (float*)(ws + 12 * MB);       // 1 MB
    float* hwA     = (float*)(ws + 13 * MB);       // 1 MB
    float* hwB     = (float*)(ws + 14 * MB);       // 1 MB
    float* ssA     = (float*)(ws + 15 * MB);
    float* sdA     = (float*)(ws + 15 * MB + 65536);
    float* ssB     = (float*)(ws + 15 * MB + 131072);
    float* sdB     = (float*)(ws + 15 * MB + 196608);
    float* accum   = (float*)(ws + 16 * MB);
    int*   done    = (int*)  (ws + 16 * MB + 64);

    prep_kernel<<<1536, 256, 0, stream>>>(adj, timestep, arrivals, departures, hard,
                                          emb_w1, emb_b1, emb_w2, emb_b2,
                                          gat_w, gat_asrc, gat_adst,
                                          nbr2, cnt2, x, hwA, ssA, sdA, accum, done);
    compact_agg_tr<<<N / 4, 256, 0, stream>>>(nbr2, cnt2, hwA, ssA, sdA, gat_b,
                                              gat_w + 64 * 64, gat_asrc + 64,
                                              gat_adst + 64,
                                              nbr_c, deg_arr, hwB, ssB, sdB);
    agg_tr<<<N / 4, 256, 0, stream>>>(hwB, ssB, sdB, nbr_c, deg_arr, gat_b + 64,
                                      gat_w + 2 * 64 * 64, gat_asrc + 128,
                                      gat_adst + 128, hwA, ssA, sdA);
    agg_final_finish<<<N / 4, 256, 0, stream>>>(hwA, ssA, sdA, nbr_c, deg_arr,
                                                gat_b + 128, x, val_w, val_b,
                                                accum, done, (float*)d_out);
    (void)in_sizes; (void)n_in; (void)out_size; (void)ws_size;
}

// Round 7
// 194.046 us; speedup vs baseline: 4.3335x; 1.2382x over previous
//
#include <hip/hip_runtime.h>
#include <math.h>

#define N 4096
#define NB 128         // bands per column
#define BANDSZ 32      // rows per band
#define KB 8           // slots per (col, band) cell
#define MAXDEG 128
#define NEG_SLOPE 0.2f
#define LN_EPS 1e-5f

__device__ __forceinline__ float wave_reduce_sum(float v) {
    #pragma unroll
    for (int m = 32; m >= 1; m >>= 1) v += __shfl_xor(v, m, 64);
    return v;
}
__device__ __forceinline__ float wave_reduce_max(float v) {
    #pragma unroll
    for (int m = 32; m >= 1; m >>= 1) v = fmaxf(v, __shfl_xor(v, m, 64));
    return v;
}

// row-vector (lane=col) times 64x64 row-major W via shfl broadcast.
__device__ __forceinline__ float transform_row(float hv, const float* __restrict__ W,
                                               int lane) {
    float tr = 0.f;
    #pragma unroll
    for (int k = 0; k < 64; ++k)
        tr += __shfl(hv, k, 64) * W[k * 64 + lane];
    return tr;
}

// softmax over neighbors (j0: first 64, j1: next 64, deg total) + weighted
// aggregation of hwin rows + bias. Indices/probs broadcast via shfl.
__device__ __forceinline__ float agg_core(int j0, int j1, int deg, float sd,
        const float* __restrict__ ssin, const float* __restrict__ hwin,
        const float* __restrict__ b, int lane) {
    float e0 = -1e30f, e1 = -1e30f;
    if (lane < deg)      { float v = ssin[j0] + sd; e0 = v > 0.f ? v : NEG_SLOPE * v; }
    if (lane + 64 < deg) { float v = ssin[j1] + sd; e1 = v > 0.f ? v : NEG_SLOPE * v; }
    float m = wave_reduce_max(fmaxf(e0, e1));
    float p0 = (lane < deg)      ? expf(e0 - m) : 0.f;
    float p1 = (lane + 64 < deg) ? expf(e1 - m) : 0.f;
    float Z = wave_reduce_sum(p0 + p1);
    float acc = 0.f;
    int d0 = min(deg, 64);
    #pragma unroll 4
    for (int n = 0; n < d0; ++n) {
        int   jj = __shfl(j0, n, 64);
        float p  = __shfl(p0, n, 64);
        acc += p * hwin[jj * 64 + lane];
    }
    for (int n = 64; n < deg; ++n) {
        int   jj = __shfl(j1, n - 64, 64);
        float p  = __shfl(p1, n - 64, 64);
        acc += p * hwin[jj * 64 + lane];
    }
    return acc / Z + b[lane];
}

// ---- dispatch 1: banded neighbor build (atomic-free, batched float4 loads)
// + emb MLP + layer-0 transform.
// Blocks [0,512): build — thread owns 4 consecutive cols x one 32-row band.
// Loads 8 float4 into registers per batch (no branches), then tests:
// 4 vmcnt waits/thread instead of 128 (the R6 mistake).
// Blocks [512,1536): emb+tr0 (independent, merged to save a dispatch).
__global__ void __launch_bounds__(256) prep_kernel(
        const float4* __restrict__ adj4, const int* __restrict__ timestep,
        const float* __restrict__ arr, const float* __restrict__ dep,
        const float* __restrict__ hard,
        const float* __restrict__ w1, const float* __restrict__ b1,
        const float* __restrict__ w2, const float* __restrict__ b2,
        const float* __restrict__ W0, const float* __restrict__ asrc,
        const float* __restrict__ adst,
        int* __restrict__ nbr2, int* __restrict__ cnt2,
        float* __restrict__ x, float* __restrict__ hwA,
        float* __restrict__ ssA, float* __restrict__ sdA,
        float* __restrict__ accum, int* __restrict__ done) {
    int wave = threadIdx.x >> 6;
    int lane = threadIdx.x & 63;
    if (blockIdx.x < 512) {
        int t    = blockIdx.x * 256 + threadIdx.x;   // 0..131071
        int cg   = t & 1023;                          // col group (4 cols)
        int band = t >> 10;                           // 0..127
        int i0   = cg * 4;
        int jbase = band * BANDSZ;
        int lc0 = 0, lc1 = 0, lc2 = 0, lc3 = 0;
        int b0 = (i0 * NB + band) * KB;
        int b1 = ((i0 + 1) * NB + band) * KB;
        int b2_ = ((i0 + 2) * NB + band) * KB;
        int b3 = ((i0 + 3) * NB + band) * KB;
        #pragma unroll
        for (int batch = 0; batch < 4; ++batch) {
            float4 a[8];
            #pragma unroll
            for (int u = 0; u < 8; ++u)
                a[u] = adj4[(size_t)(jbase + batch * 8 + u) * 1024 + cg];
            #pragma unroll
            for (int u = 0; u < 8; ++u) {
                int j = jbase + batch * 8 + u;
                if (a[u].x != 0.f || j == i0)     { if (lc0 < KB) nbr2[b0  + lc0] = j; ++lc0; }
                if (a[u].y != 0.f || j == i0 + 1) { if (lc1 < KB) nbr2[b1  + lc1] = j; ++lc1; }
                if (a[u].z != 0.f || j == i0 + 2) { if (lc2 < KB) nbr2[b2_ + lc2] = j; ++lc2; }
                if (a[u].w != 0.f || j == i0 + 3) { if (lc3 < KB) nbr2[b3  + lc3] = j; ++lc3; }
            }
        }
        cnt2[ i0      * NB + band] = lc0 < KB ? lc0 : KB;
        cnt2[(i0 + 1) * NB + band] = lc1 < KB ? lc1 : KB;
        cnt2[(i0 + 2) * NB + band] = lc2 < KB ? lc2 : KB;
        cnt2[(i0 + 3) * NB + band] = lc3 < KB ? lc3 : KB;
        if (blockIdx.x == 0 && threadIdx.x == 0) { *accum = 0.f; *done = 0; }
    } else {
        int row = (blockIdx.x - 512) * 4 + wave;
        float ts = (float)(*timestep);
        float pr = (ts - arr[row]) / (dep[row] - arr[row]);
        float hd = hard[row];
        float t  = pr * w1[lane] + hd * w1[64 + lane] + b1[lane];
        float xv = b2[lane];
        #pragma unroll
        for (int k = 0; k < 64; ++k)
            xv += __shfl(t, k, 64) * w2[k * 64 + lane];
        x[row * 64 + lane] = xv;
        float tr = transform_row(xv, W0, lane);
        hwA[row * 64 + lane] = tr;
        float s1 = wave_reduce_sum(tr * asrc[lane]);
        float s2 = wave_reduce_sum(tr * adst[lane]);
        if (lane == 0) { ssA[row] = s1; sdA[row] = s2; }
    }
}

// ---- dispatch 2: compact banded lists (lane owns 2 bands; wave prefix scan)
// + layer-0 aggregate + relu + layer-1 transform + scores.
__global__ void __launch_bounds__(256) compact_agg_tr(
        const int* __restrict__ nbr2, const int* __restrict__ cnt2,
        const float* __restrict__ hwin, const float* __restrict__ ssin,
        const float* __restrict__ sdin, const float* __restrict__ b,
        const float* __restrict__ W, const float* __restrict__ asrc,
        const float* __restrict__ adst,
        int* __restrict__ nbr_c, int* __restrict__ deg_arr,
        float* __restrict__ hwout, float* __restrict__ ssout,
        float* __restrict__ sdout) {
    __shared__ int lds[4][MAXDEG];
    int wave = threadIdx.x >> 6;
    int lane = threadIdx.x & 63;
    int i = blockIdx.x * 4 + wave;
    int c0 = min(cnt2[i * NB + 2 * lane],     KB);
    int c1 = min(cnt2[i * NB + 2 * lane + 1], KB);
    int c  = c0 + c1;
    int inc = c;
    #pragma unroll
    for (int s = 1; s < 64; s <<= 1) {
        int t = __shfl_up(inc, s, 64);
        if (lane >= s) inc += t;
    }
    int off = inc - c;
    int deg = min(__shfl(inc, 63, 64), MAXDEG);
    {
        int base0 = (i * NB + 2 * lane) * KB;
        for (int k = 0; k < c0; ++k) {
            int o = off + k;
            if (o < MAXDEG) lds[wave][o] = nbr2[base0 + k];
        }
        int base1 = (i * NB + 2 * lane + 1) * KB;
        for (int k = 0; k < c1; ++k) {
            int o = off + c0 + k;
            if (o < MAXDEG) lds[wave][o] = nbr2[base1 + k];
        }
    }
    __syncthreads();
    int j0 = (lane < deg)      ? lds[wave][lane]      : 0;
    int j1 = (lane + 64 < deg) ? lds[wave][lane + 64] : 0;
    if (lane < deg)      nbr_c[i * MAXDEG + lane]      = j0;
    if (lane + 64 < deg) nbr_c[i * MAXDEG + lane + 64] = j1;
    if (lane == 0) deg_arr[i] = deg;
    float hv = fmaxf(agg_core(j0, j1, deg, sdin[i], ssin, hwin, b, lane), 0.f);
    float tr = transform_row(hv, W, lane);
    hwout[i * 64 + lane] = tr;
    float s1 = wave_reduce_sum(tr * asrc[lane]);
    float s2 = wave_reduce_sum(tr * adst[lane]);
    if (lane == 0) { ssout[i] = s1; sdout[i] = s2; }
}

// ---- dispatch 3: layer-1 aggregate + relu + layer-2 transform + scores.
__global__ void __launch_bounds__(256) agg_tr(
        const float* __restrict__ hwin, const float* __restrict__ ssin,
        const float* __restrict__ sdin, const int* __restrict__ nbr_c,
        const int* __restrict__ deg_arr, const float* __restrict__ b,
        const float* __restrict__ W, const float* __restrict__ asrc,
        const float* __restrict__ adst,
        float* __restrict__ hwout, float* __restrict__ ssout,
        float* __restrict__ sdout) {
    int wave = threadIdx.x >> 6;
    int lane = threadIdx.x & 63;
    int i = blockIdx.x * 4 + wave;
    int deg = deg_arr[i];
    int j0 = (lane < deg)      ? nbr_c[i * MAXDEG + lane]      : 0;
    int j1 = (lane + 64 < deg) ? nbr_c[i * MAXDEG + lane + 64] : 0;
    float hv = fmaxf(agg_core(j0, j1, deg, sdin[i], ssin, hwin, b, lane), 0.f);
    float tr = transform_row(hv, W, lane);
    hwout[i * 64 + lane] = tr;
    float s1 = wave_reduce_sum(tr * asrc[lane]);
    float s2 = wave_reduce_sum(tr * adst[lane]);
    if (lane == 0) { ssout[i] = s1; sdout[i] = s2; }
}

// ---- dispatch 4: layer-2 aggregate + residual + layernorm + val_w dot +
// block atomicAdd + last-block finish (accum/done pre-zeroed by dispatch 1).
__global__ void __launch_bounds__(256) agg_final_finish(
        const float* __restrict__ hwin, const float* __restrict__ ssin,
        const float* __restrict__ sdin, const int* __restrict__ nbr_c,
        const int* __restrict__ deg_arr, const float* __restrict__ b,
        const float* __restrict__ x, const float* __restrict__ vw,
        const float* __restrict__ vb,
        float* __restrict__ accum, int* __restrict__ done,
        float* __restrict__ out) {
    __shared__ float sp[4];
    int wave = threadIdx.x >> 6;
    int lane = threadIdx.x & 63;
    int i = blockIdx.x * 4 + wave;
    int deg = deg_arr[i];
    int j0 = (lane < deg)      ? nbr_c[i * MAXDEG + lane]      : 0;
    int j1 = (lane + 64 < deg) ? nbr_c[i * MAXDEG + lane + 64] : 0;
    float hv = agg_core(j0, j1, deg, sdin[i], ssin, hwin, b, lane);
    float v  = x[i * 64 + lane] + hv;
    float mu = wave_reduce_sum(v) * (1.f / 64.f);
    float d  = v - mu;
    float var = wave_reduce_sum(d * d) * (1.f / 64.f);
    float ln  = d * rsqrtf(var + LN_EPS);
    float part = wave_reduce_sum(ln * vw[lane]);
    if (lane == 0) sp[wave] = part;
    __syncthreads();
    if (threadIdx.x == 0) {
        float bp = sp[0] + sp[1] + sp[2] + sp[3];
        atomicAdd(accum, bp);
        __threadfence();
        int old = atomicAdd(done, 1);
        if (old == (N / 4) - 1) {
            float t = __hip_atomic_load(accum, __ATOMIC_RELAXED,
                                        __HIP_MEMORY_SCOPE_AGENT);
            out[0] = fmaxf(t * (1.f / (float)N) + vb[0], 0.f);
        }
    }
}

extern "C" void kernel_launch(void* const* d_in, const int* in_sizes, int n_in,
                              void* d_out, int out_size, void* d_ws, size_t ws_size,
                              hipStream_t stream) {
    const float4* adj4      = (const float4*)d_in[0];
    const int*   timestep   = (const int*)  d_in[1];
    const float* arrivals   = (const float*)d_in[2];
    const float* departures = (const float*)d_in[3];
    const float* hard       = (const float*)d_in[4];
    // d_in[5] active_agents: unused by reference
    const float* emb_w1     = (const float*)d_in[6];
    const float* emb_b1     = (const float*)d_in[7];
    const float* emb_w2     = (const float*)d_in[8];
    const float* emb_b2     = (const float*)d_in[9];
    const float* gat_w      = (const float*)d_in[10];
    const float* gat_asrc   = (const float*)d_in[11];
    const float* gat_adst   = (const float*)d_in[12];
    const float* gat_b      = (const float*)d_in[13];
    const float* val_w      = (const float*)d_in[14];
    const float* val_b      = (const float*)d_in[15];

    const size_t MB = 1u << 20;
    char* ws = (char*)d_ws;
    int*   nbr2    = (int*)  (ws);                 // 16 MB (4096*128*8 ints)
    int*   cnt2    = (int*)  (ws + 16 * MB);       // 2 MB
    int*   nbr_c   = (int*)  (ws + 18 * MB);       // 2 MB
    int*   deg_arr = (int*)  (ws + 20 * MB);       // 16 KB
    float* x       = (float*)(ws + 21 * MB);       // 1 MB
    float* hwA     = (float*)(ws + 22 * MB);       // 1 MB
    float* hwB     = (float*)(ws + 23 * MB);       // 1 MB
    float* ssA     = (float*)(ws + 24 * MB);
    float* sdA     = (float*)(ws + 24 * MB + 65536);
    float* ssB     = (float*)(ws + 24 * MB + 131072);
    float* sdB     = (float*)(ws + 24 * MB + 196608);
    float* accum   = (float*)(ws + 25 * MB);
    int*   done    = (int*)  (ws + 25 * MB + 64);

    prep_kernel<<<1536, 256, 0, stream>>>(adj4, timestep, arrivals, departures, hard,
                                          emb_w1, emb_b1, emb_w2, emb_b2,
                                          gat_w, gat_asrc, gat_adst,
                                          nbr2, cnt2, x, hwA, ssA, sdA, accum, done);
    compact_agg_tr<<<N / 4, 256, 0, stream>>>(nbr2, cnt2, hwA, ssA, sdA, gat_b,
                                              gat_w + 64 * 64, gat_asrc + 64,
                                              gat_adst + 64,
                                              nbr_c, deg_arr, hwB, ssB, sdB);
    agg_tr<<<N / 4, 256, 0, stream>>>(hwB, ssB, sdB, nbr_c, deg_arr, gat_b + 64,
                                      gat_w + 2 * 64 * 64, gat_asrc + 128,
                                      gat_adst + 128, hwA, ssA, sdA);
    agg_final_finish<<<N / 4, 256, 0, stream>>>(hwA, ssA, sdA, nbr_c, deg_arr,
                                                gat_b + 128, x, val_w, val_b,
                                                accum, done, (float*)d_out);
    (void)in_sizes; (void)n_in; (void)out_size; (void)ws_size;
}